// Round 10
// baseline (177.723 us; speedup 1.0000x reference)
//
#include <hip/hip_runtime.h>
#include <hip/hip_bf16.h>
#include <stdint.h>

#define T_DIM 256
#define B_DIM 128
#define I_DIM 512
#define H_DIM 1024
#define M_DIM (T_DIM * B_DIM)

#define WPACK_BLOCKS 256   // 65536 threads: one per 8-elem granule of W image
#define BIAS_BLOCKS 512    // 2048 waves, 64 outputs each

typedef __attribute__((ext_vector_type(4))) float f32x4;
typedef __attribute__((ext_vector_type(8))) short short8;  // 8 bf16 in 4 VGPRs

__device__ inline unsigned short f2bf(float f) {
    __hip_bfloat16 h = __float2bfloat16(f);  // RNE
    unsigned short u;
    __builtin_memcpy(&u, &h, sizeof(u));
    return u;
}

// async 16B global->LDS (DMA). LDS dest lane-linear; swizzle baked into the
// packed GLOBAL image (both-sides involution, 0 bank conflicts R1-R9).
__device__ inline void gload_lds16(const void* g, void* l) {
    __builtin_amdgcn_global_load_lds(
        (const __attribute__((address_space(1))) uint32_t*)g,
        (__attribute__((address_space(3))) uint32_t*)l, 16, 0, 0);
}

template <int N>
__device__ inline void vwait() {
    if constexpr (N == 0)       asm volatile("s_waitcnt vmcnt(0)" ::: "memory");
    else if constexpr (N == 4)  asm volatile("s_waitcnt vmcnt(4)" ::: "memory");
    else                        asm volatile("s_waitcnt vmcnt(12)" ::: "memory");
}

// ---------------------------------------------------------------------------
// prep: blocks [0,256): pack W_ih f32 -> bf16 swizzled tile images (8 tiles,
//   [kst][row][slot] granules; granule (r,s) = src cols kst*64+(s^(r&7))*8).
// blocks [256,768): wave-cooperative bias (R9-proven):
//   biasall[b][h] = hidden[b,:].W_hh[h,:] + b_ih[h] + b_hh[h]  (f32 exact).
// ---------------------------------------------------------------------------
__global__ __launch_bounds__(256) void prep(
    const float* __restrict__ W_ih, unsigned short* __restrict__ Wp,
    const float* __restrict__ hidden, const float* __restrict__ W_hh,
    const float* __restrict__ b_ih, const float* __restrict__ b_hh,
    float* __restrict__ biasall) {
    const int bid = blockIdx.x;
    const int tid = threadIdx.x;

    if (bid < WPACK_BLOCKS) {
        int id = bid * 256 + tid;  // 0..65535
        int slot = id & 7;
        int row = (id >> 3) & 127;
        int kst = (id >> 10) & 7;
        int wt = id >> 13;  // 0..7
        int g = slot ^ (row & 7);
        const float* s = W_ih + (size_t)(wt * 128 + row) * I_DIM + kst * 64 + g * 8;
        f32x4 lo = *(const f32x4*)s;
        f32x4 hi = *(const f32x4*)(s + 4);
        union { unsigned short us[8]; short8 v; } pk;
#pragma unroll
        for (int j = 0; j < 4; ++j) { pk.us[j] = f2bf(lo[j]); pk.us[4 + j] = f2bf(hi[j]); }
        *(short8*)(Wp + (size_t)id * 8) = pk.v;
        return;
    }

    // ---- bias path ----
    const int gw = (bid - WPACK_BLOCKS) * 4 + (tid >> 6);  // wave 0..2047
    const int lane = tid & 63;
    const int h0 = (gw >> 3) * 4;
    const int b0 = (gw & 7) * 16;

    f32x4 wreg[4][4];
#pragma unroll
    for (int hh = 0; hh < 4; ++hh)
#pragma unroll
        for (int it = 0; it < 4; ++it)
            wreg[hh][it] = *(const f32x4*)(W_hh + (size_t)(h0 + hh) * H_DIM +
                                           it * 256 + lane * 4);
    float bias2[4];
#pragma unroll
    for (int hh = 0; hh < 4; ++hh) bias2[hh] = b_ih[h0 + hh] + b_hh[h0 + hh];

#pragma unroll
    for (int b = 0; b < 16; ++b) {
        f32x4 hreg[4];
#pragma unroll
        for (int it = 0; it < 4; ++it)
            hreg[it] = *(const f32x4*)(hidden + (size_t)(b0 + b) * H_DIM +
                                       it * 256 + lane * 4);
        float s[4] = {0.f, 0.f, 0.f, 0.f};
#pragma unroll
        for (int hh = 0; hh < 4; ++hh)
#pragma unroll
            for (int it = 0; it < 4; ++it)
#pragma unroll
                for (int j = 0; j < 4; ++j) s[hh] += wreg[hh][it][j] * hreg[it][j];
#pragma unroll
        for (int m = 1; m < 64; m <<= 1)
#pragma unroll
            for (int hh = 0; hh < 4; ++hh) s[hh] += __shfl_xor(s[hh], m, 64);
        if (lane == 0) {
#pragma unroll
            for (int hh = 0; hh < 4; ++hh)
                biasall[(size_t)(b0 + b) * H_DIM + h0 + hh] = s[hh] + bias2[hh];
        }
    }
}

// ---------------------------------------------------------------------------
// gemm_dra: out[m][h] = relu(x[m].W_ih[h] + biasall[m&127][h]).
// 64x128 tile, BK=64, 256 thr (2m x 2n waves). A is NOT staged in LDS:
// fragments load DIRECTLY from x (f32) into registers, 2 K-tiles ahead
// (two named register sets, compile-time alternation), f32->bf16 cvt in
// registers right before use (VALU overlaps MFMA). B double-buffered in
// 32 KB LDS via gload_lds from the packed swizzled Wp image.
// Counted vmcnt schedule (issue order: prologue A0,A1,B0,B1; per iter
// [wait, cvtA(kt), issueA(kt+2), barrier, compute, barrier, issueB(kt+2)]):
//   wait(kt) needs A(kt),B(kt); B(kt) is youngest of the pair.
//   newer-than-B(0) = B1(4) -> vmcnt(4);  kt=1..6: A(kt+1)8+B(kt+1)4 = 12;
//   kt=7: nothing newer -> vmcnt(0).  Never drains mid-loop.
// ---------------------------------------------------------------------------
__global__ __launch_bounds__(256, 3) void gemm_dra(
    const float* __restrict__ X, const unsigned short* __restrict__ Wp,
    const float* __restrict__ biasall, float* __restrict__ C,
    float* __restrict__ Clast) {
    __shared__ unsigned short Bs[2][128 * 64];   // 16 KB each

    const int tid = threadIdx.x;
    const int lane = tid & 63;
    const int wid = tid >> 6;
    const int wm = wid >> 1, wn = wid & 1;
    const int llo = lane & 15, lhi = lane >> 4;

    // XCD-aware bijective swizzle (grid 4096 % 8 == 0): the 8 n-blocks of an
    // m-tile are consecutive within one XCD -> x rows L2-local.
    const int orig = blockIdx.x;
    const int wg = (orig & 7) * 512 + (orig >> 3);
    const int mt = wg >> 3;                      // 512 m-tiles (64 rows)
    const int nt = wg & 7;                       // 8 n-tiles (128 cols)
    const int m0 = mt * 64, n0 = nt * 128;

    // A fragment bases: row = m0 + wm*32 + mi*16 + llo, col = kt*64+ks*32+lhi*8
    const float* aB0 = X + (size_t)(m0 + wm * 32 + llo) * I_DIM + lhi * 8;
    const float* aB1 = aB0 + (size_t)16 * I_DIM;
    const unsigned short* Bbase = Wp + (size_t)nt * 65536 + (size_t)tid * 8;

    f32x4 pfa[2][2][2], pfb[2][2][2];  // [mi][ks][half], two named sets
    short8 af[2][2];                   // cvt'd A frags of current tile

    auto issueA = [&](int kt, f32x4 (&set)[2][2][2]) {
#pragma unroll
        for (int mi = 0; mi < 2; ++mi)
#pragma unroll
            for (int ks = 0; ks < 2; ++ks) {
                const float* p = (mi ? aB1 : aB0) + kt * 64 + ks * 32;
                set[mi][ks][0] = *(const f32x4*)p;
                set[mi][ks][1] = *(const f32x4*)(p + 4);
            }
    };
    auto cvtA = [&](f32x4 (&set)[2][2][2]) {
#pragma unroll
        for (int mi = 0; mi < 2; ++mi)
#pragma unroll
            for (int ks = 0; ks < 2; ++ks) {
                union { unsigned short us[8]; short8 v; } pk;
#pragma unroll
                for (int j = 0; j < 4; ++j) {
                    pk.us[j] = f2bf(set[mi][ks][0][j]);
                    pk.us[4 + j] = f2bf(set[mi][ks][1][j]);
                }
                af[mi][ks] = pk.v;
            }
    };
    auto issueB = [&](int kst, int buf) {
#pragma unroll
        for (int g = 0; g < 4; ++g)
            gload_lds16(Bbase + kst * 8192 + g * 2048,
                        (char*)Bs[buf] + (g * 256 + tid) * 16);
    };

    f32x4 acc[2][4] = {};

    auto compute = [&](int buf) {
        __builtin_amdgcn_s_setprio(1);
#pragma unroll
        for (int ks = 0; ks < 2; ++ks) {
            short8 bfv[4];
#pragma unroll
            for (int ni = 0; ni < 4; ++ni) {
                int br = wn * 64 + ni * 16 + llo;
                int slot = ((ks << 2) + lhi) ^ (br & 7);
                bfv[ni] = *(const short8*)&Bs[buf][br * 64 + slot * 8];
            }
#pragma unroll
            for (int mi = 0; mi < 2; ++mi)
#pragma unroll
                for (int ni = 0; ni < 4; ++ni)
                    acc[mi][ni] = __builtin_amdgcn_mfma_f32_16x16x32_bf16(
                        af[mi][ks], bfv[ni], acc[mi][ni], 0, 0, 0);
        }
        __builtin_amdgcn_s_setprio(0);
    };

    // prologue: A(0), A(1) to regs; B(0), B(1) to LDS — 24 vmem in flight
    issueA(0, pfa);
    issueA(1, pfb);
    issueB(0, 0);
    issueB(1, 1);

#pragma unroll
    for (int kt = 0; kt < 8; ++kt) {
        if (kt == 0)      vwait<4>();
        else if (kt < 7)  vwait<12>();
        else              vwait<0>();
        if (kt & 1) cvtA(pfb); else cvtA(pfa);          // frees the set
        if (kt + 2 < 8) { if (kt & 1) issueA(kt + 2, pfb); else issueA(kt + 2, pfa); }
        __builtin_amdgcn_s_barrier();                    // B(kt) visible
        __builtin_amdgcn_sched_barrier(0);
        compute(kt & 1);
        __builtin_amdgcn_sched_barrier(0);
        __builtin_amdgcn_s_barrier();                    // buf free
        if (kt + 2 < 8) issueB(kt + 2, kt & 1);
    }

    // epilogue: bias + relu + store (+ out_last from final 128 rows)
    const bool last_tiles = (mt >= 510);
#pragma unroll
    for (int mi = 0; mi < 2; ++mi) {
#pragma unroll
        for (int ni = 0; ni < 4; ++ni) {
            int col = n0 + wn * 64 + ni * 16 + llo;
            int rowb = m0 + wm * 32 + mi * 16 + lhi * 4;
#pragma unroll
            for (int r = 0; r < 4; ++r) {
                int row = rowb + r;
                float v = acc[mi][ni][r] + biasall[(row & 127) * H_DIM + col];
                v = fmaxf(v, 0.0f);
                C[(size_t)row * H_DIM + col] = v;
                if (last_tiles) Clast[(row & 127) * H_DIM + col] = v;
            }
        }
    }
}

// ---------------------------------------------------------------------------
// Fallback reg-staged f32 GEMM (bench-passed lineage) if ws too small.
// ---------------------------------------------------------------------------
__global__ __launch_bounds__(256, 2) void gemm_bt(
    const float* __restrict__ A, const float* __restrict__ Bm,
    int M, int N, int K, const float* __restrict__ bias0,
    float* __restrict__ C, float* __restrict__ Clast) {
    __shared__ unsigned short As[128 * 64];
    __shared__ unsigned short Bs[128 * 64];
    const int tid = threadIdx.x;
    const int wid = tid >> 6, lane = tid & 63;
    const int wr = wid >> 1, wc = wid & 1;
    const int lhi = lane >> 4, llo = lane & 15;
    const int orig = blockIdx.x, nwg = gridDim.x;
    const int wg = (nwg > 8 && (nwg & 7) == 0)
                       ? ((orig & 7) * (nwg >> 3) + (orig >> 3)) : orig;
    const int m0 = (wg >> 3) * 128, n0 = (wg & 7) * 128;
    const int srow = tid >> 3, c8 = tid & 7;
    const int slot8 = (c8 ^ (srow & 7)) * 8;
    const float* Aptr = A + (size_t)(m0 + srow) * K + c8 * 8;
    const float* Bptr = Bm + (size_t)(n0 + srow) * K + c8 * 8;
    f32x4 pf[2][4][2];
    auto issue = [&](int k0) {
#pragma unroll
        for (int g = 0; g < 4; ++g) {
            const float* pa = Aptr + (size_t)g * 32 * K + k0;
            const float* pb = Bptr + (size_t)g * 32 * K + k0;
            pf[0][g][0] = *(const f32x4*)pa; pf[0][g][1] = *(const f32x4*)(pa + 4);
            pf[1][g][0] = *(const f32x4*)pb; pf[1][g][1] = *(const f32x4*)(pb + 4);
        }
    };
    auto write_lds = [&]() {
#pragma unroll
        for (int g = 0; g < 4; ++g) {
            union { unsigned short s[8]; short8 v; } pka, pkb;
#pragma unroll
            for (int j = 0; j < 4; ++j) {
                pka.s[j] = f2bf(pf[0][g][0][j]); pka.s[4 + j] = f2bf(pf[0][g][1][j]);
                pkb.s[j] = f2bf(pf[1][g][0][j]); pkb.s[4 + j] = f2bf(pf[1][g][1][j]);
            }
            *(short8*)&As[(srow + g * 32) * 64 + slot8] = pka.v;
            *(short8*)&Bs[(srow + g * 32) * 64 + slot8] = pkb.v;
        }
    };
    f32x4 acc[4][4] = {};
    auto compute = [&]() {
#pragma unroll
        for (int ks = 0; ks < 2; ++ks) {
            short8 afr[4], bfr[4];
#pragma unroll
            for (int mi = 0; mi < 4; ++mi) {
                int ar = wr * 64 + mi * 16 + llo;
                afr[mi] = *(const short8*)&As[ar * 64 + (((ks << 2) + lhi) ^ (ar & 7)) * 8];
            }
#pragma unroll
            for (int ni = 0; ni < 4; ++ni) {
                int br = wc * 64 + ni * 16 + llo;
                bfr[ni] = *(const short8*)&Bs[br * 64 + (((ks << 2) + lhi) ^ (br & 7)) * 8];
            }
#pragma unroll
            for (int mi = 0; mi < 4; ++mi)
#pragma unroll
                for (int ni = 0; ni < 4; ++ni)
                    acc[mi][ni] = __builtin_amdgcn_mfma_f32_16x16x32_bf16(
                        afr[mi], bfr[ni], acc[mi][ni], 0, 0, 0);
        }
    };
    issue(0); write_lds(); __syncthreads();
    for (int k0 = 64; k0 < K; k0 += 64) {
        issue(k0); compute(); __syncthreads(); write_lds(); __syncthreads();
    }
    compute();
    const bool last_tile = (m0 == M - 128);
#pragma unroll
    for (int mi = 0; mi < 4; ++mi)
#pragma unroll
        for (int ni = 0; ni < 4; ++ni) {
            int col = n0 + wc * 64 + ni * 16 + llo;
            int rowb = m0 + wr * 64 + mi * 16 + lhi * 4;
#pragma unroll
            for (int r = 0; r < 4; ++r) {
                int row = rowb + r;
                float v = fmaxf(acc[mi][ni][r] + bias0[(row & 127) * N + col], 0.f);
                C[(size_t)row * N + col] = v;
                if (last_tile) Clast[(row & 127) * N + col] = v;
            }
        }
}

extern "C" void kernel_launch(void* const* d_in, const int* in_sizes, int n_in,
                              void* d_out, int out_size, void* d_ws, size_t ws_size,
                              hipStream_t stream) {
    const float* x = (const float*)d_in[0];       // (T,B,I)
    const float* hidden = (const float*)d_in[1];  // (B,H)
    const float* W_ih = (const float*)d_in[2];    // (H,I)
    const float* W_hh = (const float*)d_in[3];    // (H,H)
    const float* b_ih = (const float*)d_in[4];    // (H,)
    const float* b_hh = (const float*)d_in[5];    // (H,)

    float* out = (float*)d_out;                              // (T,B,H)
    float* out_last = out + (size_t)T_DIM * B_DIM * H_DIM;   // (B,H)

    // ws: [0,512K) biasall f32 ; [512K, 512K+1M) Wp bf16
    float* biasall = (float*)d_ws;
    unsigned short* Wp = (unsigned short*)((char*)d_ws + 512 * 1024);
    const size_t ws_need = 512 * 1024 + (size_t)H_DIM * I_DIM * 2;

    if (ws_size >= ws_need) {
        prep<<<dim3(WPACK_BLOCKS + BIAS_BLOCKS), dim3(256), 0, stream>>>(
            W_ih, Wp, hidden, W_hh, b_ih, b_hh, biasall);
        gemm_dra<<<dim3(4096), dim3(256), 0, stream>>>(x, Wp, biasall, out, out_last);
    } else {
        prep<<<dim3(WPACK_BLOCKS + BIAS_BLOCKS), dim3(256), 0, stream>>>(
            W_ih, (unsigned short*)d_ws, hidden, W_hh, b_ih, b_hh, biasall);
        gemm_bt<<<dim3(M_DIM / 128 * (H_DIM / 128)), dim3(256), 0, stream>>>(
            x, W_ih, M_DIM, H_DIM, I_DIM, biasall, out, out_last);
    }
}

// Round 11
// 120.102 us; speedup vs baseline: 1.4798x; 1.4798x over previous
//
#include <hip/hip_runtime.h>
#include <hip/hip_bf16.h>
#include <stdint.h>

#define T_DIM 256
#define B_DIM 128
#define I_DIM 512
#define H_DIM 1024
#define M_DIM (T_DIM * B_DIM)

#define WPACK_BLOCKS 256   // 65536 threads: one per 8-elem granule of W image
#define BIAS_BLOCKS 512    // 2048 waves, 64 outputs each

typedef __attribute__((ext_vector_type(4))) float f32x4;
typedef __attribute__((ext_vector_type(8))) short short8;  // 8 bf16 in 4 VGPRs

__device__ inline unsigned short f2bf(float f) {
    __hip_bfloat16 h = __float2bfloat16(f);  // RNE
    unsigned short u;
    __builtin_memcpy(&u, &h, sizeof(u));
    return u;
}

// async 16B global->LDS (DMA). LDS dest lane-linear; swizzle baked into the
// GLOBAL source address (both-sides involution; 0 bank conflicts R1-R10).
__device__ inline void gload_lds16(const void* g, void* l) {
    __builtin_amdgcn_global_load_lds(
        (const __attribute__((address_space(1))) uint32_t*)g,
        (__attribute__((address_space(3))) uint32_t*)l, 16, 0, 0);
}

// ---------------------------------------------------------------------------
// prep: blocks [0,256): pack W_ih f32 -> bf16 swizzled tile images (8 tiles,
//   [kst][row][slot] granules; granule (r,s) = src cols kst*64+(s^(r&7))*8).
// blocks [256,768): wave-cooperative bias (R9-proven):
//   biasall[b][h] = hidden[b,:].W_hh[h,:] + b_ih[h] + b_hh[h]  (f32 exact).
// ---------------------------------------------------------------------------
__global__ __launch_bounds__(256) void prep(
    const float* __restrict__ W_ih, unsigned short* __restrict__ Wp,
    const float* __restrict__ hidden, const float* __restrict__ W_hh,
    const float* __restrict__ b_ih, const float* __restrict__ b_hh,
    float* __restrict__ biasall) {
    const int bid = blockIdx.x;
    const int tid = threadIdx.x;

    if (bid < WPACK_BLOCKS) {
        int id = bid * 256 + tid;  // 0..65535
        int slot = id & 7;
        int row = (id >> 3) & 127;
        int kst = (id >> 10) & 7;
        int wt = id >> 13;  // 0..7
        int g = slot ^ (row & 7);
        const float* s = W_ih + (size_t)(wt * 128 + row) * I_DIM + kst * 64 + g * 8;
        f32x4 lo = *(const f32x4*)s;
        f32x4 hi = *(const f32x4*)(s + 4);
        union { unsigned short us[8]; short8 v; } pk;
#pragma unroll
        for (int j = 0; j < 4; ++j) { pk.us[j] = f2bf(lo[j]); pk.us[4 + j] = f2bf(hi[j]); }
        *(short8*)(Wp + (size_t)id * 8) = pk.v;
        return;
    }

    // ---- bias path ----
    const int gw = (bid - WPACK_BLOCKS) * 4 + (tid >> 6);  // wave 0..2047
    const int lane = tid & 63;
    const int h0 = (gw >> 3) * 4;
    const int b0 = (gw & 7) * 16;

    f32x4 wreg[4][4];
#pragma unroll
    for (int hh = 0; hh < 4; ++hh)
#pragma unroll
        for (int it = 0; it < 4; ++it)
            wreg[hh][it] = *(const f32x4*)(W_hh + (size_t)(h0 + hh) * H_DIM +
                                           it * 256 + lane * 4);
    float bias2[4];
#pragma unroll
    for (int hh = 0; hh < 4; ++hh) bias2[hh] = b_ih[h0 + hh] + b_hh[h0 + hh];

#pragma unroll
    for (int b = 0; b < 16; ++b) {
        f32x4 hreg[4];
#pragma unroll
        for (int it = 0; it < 4; ++it)
            hreg[it] = *(const f32x4*)(hidden + (size_t)(b0 + b) * H_DIM +
                                       it * 256 + lane * 4);
        float s[4] = {0.f, 0.f, 0.f, 0.f};
#pragma unroll
        for (int hh = 0; hh < 4; ++hh)
#pragma unroll
            for (int it = 0; it < 4; ++it)
#pragma unroll
                for (int j = 0; j < 4; ++j) s[hh] += wreg[hh][it][j] * hreg[it][j];
#pragma unroll
        for (int m = 1; m < 64; m <<= 1)
#pragma unroll
            for (int hh = 0; hh < 4; ++hh) s[hh] += __shfl_xor(s[hh], m, 64);
        if (lane == 0) {
#pragma unroll
            for (int hh = 0; hh < 4; ++hh)
                biasall[(size_t)(b0 + b) * H_DIM + h0 + hh] = s[hh] + bias2[hh];
        }
    }
}

// ---------------------------------------------------------------------------
// gemm_f32a: out[m][h] = relu(x[m].W_ih[h] + biasall[m&127][h]).
// 64x128 tile, BK=64, 256 thr (2m x 2n waves).
// A: staged as F32 directly from x via gload_lds (no pre-pass, x read once,
//    coalesced: each wave covers 4 full 256B row segments). Source address
//    pre-swizzled (granule cs = (tid&15)^(tid>>4)); fragment read uses
//    slot = g ^ (row&15)  (R3-proven: 0 bank conflicts). f32->bf16 cvt at
//    fragment-read time (VALU overlaps MFMA across waves, m114).
// B: bf16 dbuf from packed swizzled Wp image (R8/R9-proven).
// LDS 64 KB (A 2x16 KB f32 + B 2x16 KB bf16) -> 2 blocks/CU.
// Counted vmcnt: 8 loads/K-step (4 A + 4 B); wait vmcnt(8) keeps the next
// tile's loads in flight across barriers; drains only at the tail (R8 gemm64
// schedule verbatim, 6->8 loads).
// ---------------------------------------------------------------------------
__global__ __launch_bounds__(256, 2) void gemm_f32a(
    const float* __restrict__ X, const unsigned short* __restrict__ Wp,
    const float* __restrict__ biasall, float* __restrict__ C,
    float* __restrict__ Clast) {
    __shared__ float Af[2][64 * 64];             // 16 KB each
    __shared__ unsigned short Bs[2][128 * 64];   // 16 KB each

    const int tid = threadIdx.x;
    const int lane = tid & 63;
    const int wid = tid >> 6;
    const int wm = wid >> 1, wn = wid & 1;
    const int llo = lane & 15, lhi = lane >> 4;

    // XCD-aware bijective swizzle (grid 4096 % 8 == 0)
    const int orig = blockIdx.x;
    const int wg = (orig & 7) * 512 + (orig >> 3);
    const int mt = wg >> 3;                      // 512 m-tiles (64 rows)
    const int nt = wg & 7;                       // 8 n-tiles (128 cols)
    const int m0 = mt * 64, n0 = nt * 128;

    // A staging: thread covers rows (tid>>4)+g*16, source granule (tid&15)^(tid>>4)
    const float* Abase =
        X + (size_t)(m0 + (tid >> 4)) * I_DIM + (((tid & 15) ^ (tid >> 4)) << 2);
    const unsigned short* Bbase = Wp + (size_t)nt * 65536 + (size_t)tid * 8;

    auto stage = [&](int kt, int buf) {
#pragma unroll
        for (int g = 0; g < 4; ++g)
            gload_lds16(Abase + (size_t)g * 16 * I_DIM + kt * 64,
                        (char*)Af[buf] + (g * 256 + tid) * 16);
#pragma unroll
        for (int g = 0; g < 4; ++g)
            gload_lds16(Bbase + kt * 8192 + g * 2048,
                        (char*)Bs[buf] + (g * 256 + tid) * 16);
    };

    f32x4 acc[2][4] = {};

    auto compute = [&](int buf) {
        __builtin_amdgcn_s_setprio(1);
#pragma unroll
        for (int ks = 0; ks < 2; ++ks) {
            short8 af[2], bfv[4];
#pragma unroll
            for (int mi = 0; mi < 2; ++mi) {
                int ar = wm * 32 + mi * 16 + llo;
                int g0 = ks * 8 + lhi * 2;
                const float* base = &Af[buf][ar * 64];
                f32x4 a0 = *(const f32x4*)(base + ((g0 ^ (ar & 15)) << 2));
                f32x4 a1 = *(const f32x4*)(base + (((g0 + 1) ^ (ar & 15)) << 2));
                union { unsigned short us[8]; short8 v; } pk;
#pragma unroll
                for (int j = 0; j < 4; ++j) {
                    pk.us[j] = f2bf(a0[j]);
                    pk.us[4 + j] = f2bf(a1[j]);
                }
                af[mi] = pk.v;
            }
#pragma unroll
            for (int ni = 0; ni < 4; ++ni) {
                int br = wn * 64 + ni * 16 + llo;
                int slot = ((ks << 2) + lhi) ^ (br & 7);
                bfv[ni] = *(const short8*)&Bs[buf][br * 64 + slot * 8];
            }
#pragma unroll
            for (int mi = 0; mi < 2; ++mi)
#pragma unroll
                for (int ni = 0; ni < 4; ++ni)
                    acc[mi][ni] = __builtin_amdgcn_mfma_f32_16x16x32_bf16(
                        af[mi], bfv[ni], acc[mi][ni], 0, 0, 0);
        }
        __builtin_amdgcn_s_setprio(0);
    };

    stage(0, 0);   // 8 loads in flight
    stage(1, 1);   // 16 in flight
#pragma unroll
    for (int kt = 0; kt < 8; ++kt) {
        const int buf = kt & 1;
        if (kt < 7)
            asm volatile("s_waitcnt vmcnt(8)" ::: "memory");  // tile kt landed
        else
            asm volatile("s_waitcnt vmcnt(0)" ::: "memory");
        __builtin_amdgcn_s_barrier();
        __builtin_amdgcn_sched_barrier(0);
        compute(buf);
        __builtin_amdgcn_sched_barrier(0);
        __builtin_amdgcn_s_barrier();             // buf free for reuse
        if (kt + 2 < 8) stage(kt + 2, buf);       // stays in flight across iters
    }

    // epilogue: bias + relu + store (+ out_last from final 128 rows)
    const bool last_tiles = (mt >= 510);
#pragma unroll
    for (int mi = 0; mi < 2; ++mi) {
#pragma unroll
        for (int ni = 0; ni < 4; ++ni) {
            int col = n0 + wn * 64 + ni * 16 + llo;
            int rowb = m0 + wm * 32 + mi * 16 + lhi * 4;
#pragma unroll
            for (int r = 0; r < 4; ++r) {
                int row = rowb + r;
                float v = acc[mi][ni][r] + biasall[(row & 127) * H_DIM + col];
                v = fmaxf(v, 0.0f);
                C[(size_t)row * H_DIM + col] = v;
                if (last_tiles) Clast[(row & 127) * H_DIM + col] = v;
            }
        }
    }
}

// ---------------------------------------------------------------------------
// Fallback reg-staged f32 GEMM (bench-passed lineage) if ws too small.
// ---------------------------------------------------------------------------
__global__ __launch_bounds__(256, 2) void gemm_bt(
    const float* __restrict__ A, const float* __restrict__ Bm,
    int M, int N, int K, const float* __restrict__ bias0,
    float* __restrict__ C, float* __restrict__ Clast) {
    __shared__ unsigned short As[128 * 64];
    __shared__ unsigned short Bs[128 * 64];
    const int tid = threadIdx.x;
    const int wid = tid >> 6, lane = tid & 63;
    const int wr = wid >> 1, wc = wid & 1;
    const int lhi = lane >> 4, llo = lane & 15;
    const int orig = blockIdx.x, nwg = gridDim.x;
    const int wg = (nwg > 8 && (nwg & 7) == 0)
                       ? ((orig & 7) * (nwg >> 3) + (orig >> 3)) : orig;
    const int m0 = (wg >> 3) * 128, n0 = (wg & 7) * 128;
    const int srow = tid >> 3, c8 = tid & 7;
    const int slot8 = (c8 ^ (srow & 7)) * 8;
    const float* Aptr = A + (size_t)(m0 + srow) * K + c8 * 8;
    const float* Bptr = Bm + (size_t)(n0 + srow) * K + c8 * 8;
    f32x4 pf[2][4][2];
    auto issue = [&](int k0) {
#pragma unroll
        for (int g = 0; g < 4; ++g) {
            const float* pa = Aptr + (size_t)g * 32 * K + k0;
            const float* pb = Bptr + (size_t)g * 32 * K + k0;
            pf[0][g][0] = *(const f32x4*)pa; pf[0][g][1] = *(const f32x4*)(pa + 4);
            pf[1][g][0] = *(const f32x4*)pb; pf[1][g][1] = *(const f32x4*)(pb + 4);
        }
    };
    auto write_lds = [&]() {
#pragma unroll
        for (int g = 0; g < 4; ++g) {
            union { unsigned short s[8]; short8 v; } pka, pkb;
#pragma unroll
            for (int j = 0; j < 4; ++j) {
                pka.s[j] = f2bf(pf[0][g][0][j]); pka.s[4 + j] = f2bf(pf[0][g][1][j]);
                pkb.s[j] = f2bf(pf[1][g][0][j]); pkb.s[4 + j] = f2bf(pf[1][g][1][j]);
            }
            *(short8*)&As[(srow + g * 32) * 64 + slot8] = pka.v;
            *(short8*)&Bs[(srow + g * 32) * 64 + slot8] = pkb.v;
        }
    };
    f32x4 acc[4][4] = {};
    auto compute = [&]() {
#pragma unroll
        for (int ks = 0; ks < 2; ++ks) {
            short8 afr[4], bfr[4];
#pragma unroll
            for (int mi = 0; mi < 4; ++mi) {
                int ar = wr * 64 + mi * 16 + llo;
                afr[mi] = *(const short8*)&As[ar * 64 + (((ks << 2) + lhi) ^ (ar & 7)) * 8];
            }
#pragma unroll
            for (int ni = 0; ni < 4; ++ni) {
                int br = wc * 64 + ni * 16 + llo;
                bfr[ni] = *(const short8*)&Bs[br * 64 + (((ks << 2) + lhi) ^ (br & 7)) * 8];
            }
#pragma unroll
            for (int mi = 0; mi < 4; ++mi)
#pragma unroll
                for (int ni = 0; ni < 4; ++ni)
                    acc[mi][ni] = __builtin_amdgcn_mfma_f32_16x16x32_bf16(
                        afr[mi], bfr[ni], acc[mi][ni], 0, 0, 0);
        }
    };
    issue(0); write_lds(); __syncthreads();
    for (int k0 = 64; k0 < K; k0 += 64) {
        issue(k0); compute(); __syncthreads(); write_lds(); __syncthreads();
    }
    compute();
    const bool last_tile = (m0 == M - 128);
#pragma unroll
    for (int mi = 0; mi < 4; ++mi)
#pragma unroll
        for (int ni = 0; ni < 4; ++ni) {
            int col = n0 + wc * 64 + ni * 16 + llo;
            int rowb = m0 + wr * 64 + mi * 16 + lhi * 4;
#pragma unroll
            for (int r = 0; r < 4; ++r) {
                int row = rowb + r;
                float v = fmaxf(acc[mi][ni][r] + bias0[(row & 127) * N + col], 0.f);
                C[(size_t)row * N + col] = v;
                if (last_tile) Clast[(row & 127) * N + col] = v;
            }
        }
}

extern "C" void kernel_launch(void* const* d_in, const int* in_sizes, int n_in,
                              void* d_out, int out_size, void* d_ws, size_t ws_size,
                              hipStream_t stream) {
    const float* x = (const float*)d_in[0];       // (T,B,I)
    const float* hidden = (const float*)d_in[1];  // (B,H)
    const float* W_ih = (const float*)d_in[2];    // (H,I)
    const float* W_hh = (const float*)d_in[3];    // (H,H)
    const float* b_ih = (const float*)d_in[4];    // (H,)
    const float* b_hh = (const float*)d_in[5];    // (H,)

    float* out = (float*)d_out;                              // (T,B,H)
    float* out_last = out + (size_t)T_DIM * B_DIM * H_DIM;   // (B,H)

    // ws: [0,512K) biasall f32 ; [512K, 512K+1M) Wp bf16
    float* biasall = (float*)d_ws;
    unsigned short* Wp = (unsigned short*)((char*)d_ws + 512 * 1024);
    const size_t ws_need = 512 * 1024 + (size_t)H_DIM * I_DIM * 2;

    prep<<<dim3(WPACK_BLOCKS + BIAS_BLOCKS), dim3(256), 0, stream>>>(
        W_ih, Wp, hidden, W_hh, b_ih, b_hh, biasall);

    if (ws_size >= ws_need) {
        gemm_f32a<<<dim3(4096), dim3(256), 0, stream>>>(x, Wp, biasall, out, out_last);
    } else {
        gemm_bt<<<dim3(M_DIM / 128 * (H_DIM / 128)), dim3(256), 0, stream>>>(
            x, W_ih, M_DIM, H_DIM, I_DIM, biasall, out, out_last);
    }
}